// Round 9
// baseline (234.157 us; speedup 1.0000x reference)
//
#include <hip/hip_runtime.h>
#include <hip/hip_bf16.h>

#define N_NODES 100000
#define N_EDGES 3200000
#define F_IN    512
#define F_H     16
#define F_OUT   7
#define NB      391                 // buckets of 256 dst nodes
#define GPART   512                 // partition blocks
#define PER_BLK 6256                // multiple of 4; 512*6256 >= 3.2M (last block short)
#define CAPB    10240               // LDS stage cap per bucket (mean 8184, sigma~90)
#define WTS     516                 // padded Wt stride (floats)

typedef unsigned int u32;

static __device__ __forceinline__ float bflo(u32 u) { return __uint_as_float(u << 16); }
static __device__ __forceinline__ float bfhi(u32 u) { return __uint_as_float(u & 0xFFFF0000u); }
static __device__ __forceinline__ unsigned short f2bf(float f) {
  u32 x = __float_as_uint(f);
  x += 0x7FFF + ((x >> 16) & 1);    // round-to-nearest-even (finite values)
  return (unsigned short)(x >> 16);
}

// ---------------- bucket histogram (per-block rows + bucket totals) ----------------
__global__ __launch_bounds__(256) void k_hist(const int* __restrict__ dst,
                                              int* __restrict__ hist,
                                              int* __restrict__ bcnt) {
  __shared__ int h[NB];
  int tid = threadIdx.x, blk = blockIdx.x;
  for (int b = tid; b < NB; b += 256) h[b] = 0;
  __syncthreads();
  int e0 = blk * PER_BLK;
  int n = min(PER_BLK, N_EDGES - e0);            // multiple of 4
  const int4* d4 = (const int4*)(dst + e0);
  for (int i = tid; i < (n >> 2); i += 256) {
    int4 d = d4[i];
    atomicAdd(&h[d.x >> 8], 1);
    atomicAdd(&h[d.y >> 8], 1);
    atomicAdd(&h[d.z >> 8], 1);
    atomicAdd(&h[d.w >> 8], 1);
  }
  __syncthreads();
  for (int b = tid; b < NB; b += 256) {
    int c = h[b];
    hist[blk * NB + b] = c;                      // block-major per-block counts
    if (c) atomicAdd(&bcnt[b], c);               // bucket totals
  }
}

// ---------------- GEMM1: h1 = x @ W1  [N,512]x[512,16] ----------------
// 2 rows/thread, 16 rows/wave. __launch_bounds__(256,4): cap 128 VGPR ->
// no spill (acc=32 + 8 inflight float4 = 32 + misc ~25) AND 4 blocks/CU
// (16 waves) for latency hiding. unroll 4 = 8 x-loads in flight.
__global__ __launch_bounds__(256, 4) void k_gemm1(const float* __restrict__ x,
                                                  const float* __restrict__ W1,
                                                  float* __restrict__ h1) {
  __shared__ __align__(16) float Wt[F_H * WTS];  // 33 KB, transposed [j][k], padded
  int tid = threadIdx.x;
  for (int idx = tid; idx < F_IN * F_H; idx += 256) {
    int k = idx >> 4, j = idx & 15;
    Wt[j * WTS + k] = W1[idx];
  }
  __syncthreads();

  int wave = tid >> 6, lane = tid & 63;
  int g = lane & 7, h = lane >> 3;
  int rowA = (blockIdx.x * 4 + wave) * 16 + h * 2;
  int rowB = rowA + 1;
  bool vA = rowA < N_NODES, vB = rowB < N_NODES;

  const float4* xa = (const float4*)(x + (size_t)(vA ? rowA : 0) * F_IN);
  const float4* xb = (const float4*)(x + (size_t)(vB ? rowB : 0) * F_IN);

  float accA[16], accB[16];
#pragma unroll
  for (int j = 0; j < 16; j++) { accA[j] = 0.f; accB[j] = 0.f; }

#pragma unroll 4
  for (int t = 0; t < 16; t++) {
    int k0 = g * 4 + t * 32;
    float4 a = xa[g + t * 8];
    float4 b = xb[g + t * 8];
#pragma unroll
    for (int j = 0; j < 16; j++) {
      float4 wv = *(const float4*)(&Wt[j * WTS + k0]);
      accA[j] += a.x * wv.x + a.y * wv.y + a.z * wv.z + a.w * wv.w;
      accB[j] += b.x * wv.x + b.y * wv.y + b.z * wv.z + b.w * wv.w;
    }
  }
#pragma unroll
  for (int off = 1; off < 8; off <<= 1)
#pragma unroll
    for (int j = 0; j < 16; j++) {
      accA[j] += __shfl_xor(accA[j], off, 64);
      accB[j] += __shfl_xor(accB[j], off, 64);
    }

  if (g == 0) {
    if (vA) {
      float4* o = (float4*)(h1 + (size_t)rowA * F_H);
      o[0] = make_float4(accA[0], accA[1], accA[2], accA[3]);
      o[1] = make_float4(accA[4], accA[5], accA[6], accA[7]);
      o[2] = make_float4(accA[8], accA[9], accA[10], accA[11]);
      o[3] = make_float4(accA[12], accA[13], accA[14], accA[15]);
    }
    if (vB) {
      float4* o = (float4*)(h1 + (size_t)rowB * F_H);
      o[0] = make_float4(accB[0], accB[1], accB[2], accB[3]);
      o[1] = make_float4(accB[4], accB[5], accB[6], accB[7]);
      o[2] = make_float4(accB[8], accB[9], accB[10], accB[11]);
      o[3] = make_float4(accB[12], accB[13], accB[14], accB[15]);
    }
  }
}

// -------- single tiny scan: bucket bases + gcur init + rowptr sentinel --------
__global__ __launch_bounds__(512) void k_scan391(const int* __restrict__ bcnt,
                                                 int* __restrict__ pbase,
                                                 int* __restrict__ gcur,
                                                 int* __restrict__ rowptr) {
  __shared__ int lds[512];
  int tid = threadIdx.x;
  int c = (tid < NB) ? bcnt[tid] : 0;
  lds[tid] = c;
  __syncthreads();
  for (int off = 1; off < 512; off <<= 1) {
    int v = (tid >= off) ? lds[tid - off] : 0;
    __syncthreads();
    lds[tid] += v;
    __syncthreads();
  }
  int ex = lds[tid] - c;
  if (tid <= NB) pbase[tid] = ex;     // pbase[NB] == N_EDGES (total)
  if (tid < NB) gcur[tid] = ex;
  if (tid == 0) rowptr[N_NODES] = N_EDGES;
}

// -------- partition scatter: reserve ranges atomically, LDS cursors --------
// pack: (dst_local << 17) | src
__global__ __launch_bounds__(256) void k_part(const int* __restrict__ src,
                                              const int* __restrict__ dst,
                                              const int* __restrict__ hist,
                                              int* __restrict__ gcur,
                                              u32* __restrict__ pairs) {
  __shared__ int lbase[NB];
  __shared__ int lcur[NB];
  int tid = threadIdx.x, blk = blockIdx.x;
  for (int b = tid; b < NB; b += 256) {
    int c = hist[blk * NB + b];
    lbase[b] = c ? atomicAdd(&gcur[b], c) : 0;
    lcur[b] = 0;
  }
  __syncthreads();
  int e0 = blk * PER_BLK;
  int n = min(PER_BLK, N_EDGES - e0);            // multiple of 4
  const int4* s4 = (const int4*)(src + e0);
  const int4* d4 = (const int4*)(dst + e0);
  for (int i = tid; i < (n >> 2); i += 256) {
    int4 sv = s4[i];
    int4 dv = d4[i];
    { int b = dv.x >> 8; u32 v = ((u32)(dv.x & 255) << 17) | (u32)sv.x;
      pairs[lbase[b] + atomicAdd(&lcur[b], 1)] = v; }
    { int b = dv.y >> 8; u32 v = ((u32)(dv.y & 255) << 17) | (u32)sv.y;
      pairs[lbase[b] + atomicAdd(&lcur[b], 1)] = v; }
    { int b = dv.z >> 8; u32 v = ((u32)(dv.z & 255) << 17) | (u32)sv.z;
      pairs[lbase[b] + atomicAdd(&lcur[b], 1)] = v; }
    { int b = dv.w >> 8; u32 v = ((u32)(dv.w & 255) << 17) | (u32)sv.w;
      pairs[lbase[b] + atomicAdd(&lcur[b], 1)] = v; }
  }
}

// ---- per-bucket CSR (pairs staged in LDS, read once) + rowptr + h1p fold ----
__global__ __launch_bounds__(512) void k_bcsr(const u32* __restrict__ pairs,
                                              const int* __restrict__ pbase,
                                              int* __restrict__ colsrc,
                                              int* __restrict__ rowptr,
                                              const float* __restrict__ h1,
                                              unsigned short* __restrict__ h1p) {
  __shared__ u32 stage[CAPB];                    // 40 KB
  __shared__ int hist256[256];
  __shared__ int scan_[256];
  __shared__ int excl[256];
  __shared__ int cur[256];
  __shared__ float sdinv[256];
  int tid = threadIdx.x, b = blockIdx.x;
  if (tid < 256) { hist256[tid] = 0; cur[tid] = 0; }
  __syncthreads();
  int base = pbase[b];
  int cnt  = pbase[b + 1] - base;
  for (int k = tid; k < cnt; k += 512) {
    u32 v = pairs[base + k];
    if (k < CAPB) stage[k] = v;
    atomicAdd(&hist256[v >> 17], 1);
  }
  __syncthreads();
  if (tid < 256) scan_[tid] = hist256[tid];
  __syncthreads();
  for (int off = 1; off < 256; off <<= 1) {
    int v = 0;
    if (tid < 256 && tid >= off) v = scan_[tid - off];
    __syncthreads();
    if (tid < 256) scan_[tid] += v;
    __syncthreads();
  }
  if (tid < 256) {
    int c = hist256[tid];
    int ex = scan_[tid] - c;
    excl[tid] = ex;
    sdinv[tid] = rsqrtf((float)(c + 1));
    int node = b * 256 + tid;
    if (node < N_NODES) rowptr[node] = base + ex;
  }
  __syncthreads();
  for (int k = tid; k < cnt; k += 512) {
    u32 v = (k < CAPB) ? stage[k] : pairs[base + k];
    int dl = v >> 17;
    colsrc[base + excl[dl] + atomicAdd(&cur[dl], 1)] = (int)(v & 0x1FFFF);
  }
  // epilogue: h1p = bf16(dinv * h1) for this bucket's nodes
  int nmax = min(256, N_NODES - b * 256);
  for (int idx = tid; idx < nmax * 16; idx += 512) {
    int ln = idx >> 4, j = idx & 15;
    size_t n = (size_t)(b * 256 + ln);
    h1p[n * 16 + j] = f2bf(h1[n * 16 + j] * sdinv[ln]);
  }
}

// ======= fused agg1 (+bias+ReLU) + GEMM2 -> gfp bf16[N][8]; dinv folded =======
// wave per node: c = lane&1 (uint4 = 8 feats of 32B row), q = lane>>1 (32 slots)
__global__ __launch_bounds__(256) void k_agg1g2(const unsigned short* __restrict__ h1p,
                                                const int* __restrict__ colsrc,
                                                const int* __restrict__ rowptr,
                                                const float* __restrict__ b1,
                                                const float* __restrict__ W2,
                                                unsigned short* __restrict__ gfp) {
  int tid = threadIdx.x;
  int wv = tid >> 6, lane = tid & 63;
  int c = lane & 1, q = lane >> 1;
  int i = blockIdx.x * 4 + wv;                   // exact grid: 25000 blocks

  int jp = lane & 7;
  bool jv = jp < 7;
  float wcol[16];
#pragma unroll
  for (int k = 0; k < 16; k++) wcol[k] = jv ? W2[k * 7 + jp] : 0.f;

  int start = rowptr[i];
  int cnt = rowptr[i + 1] - start;
  float acc[8];
#pragma unroll
  for (int k = 0; k < 8; k++) acc[k] = 0.f;

  const uint4* hp = (const uint4*)h1p;           // row i -> units i*2 + c
  for (int e = q; e < cnt; e += 32) {
    int src = colsrc[start + e];
    uint4 hv = hp[src * 2 + c];
    acc[0] += bflo(hv.x); acc[1] += bfhi(hv.x);
    acc[2] += bflo(hv.y); acc[3] += bfhi(hv.y);
    acc[4] += bflo(hv.z); acc[5] += bfhi(hv.z);
    acc[6] += bflo(hv.w); acc[7] += bfhi(hv.w);
  }
  if (q == 0) {                                  // self-loop (dinv pre-folded)
    uint4 hv = hp[i * 2 + c];
    acc[0] += bflo(hv.x); acc[1] += bfhi(hv.x);
    acc[2] += bflo(hv.y); acc[3] += bfhi(hv.y);
    acc[4] += bflo(hv.z); acc[5] += bfhi(hv.z);
    acc[6] += bflo(hv.w); acc[7] += bfhi(hv.w);
  }
#pragma unroll
  for (int off = 2; off < 64; off <<= 1)
#pragma unroll
    for (int k = 0; k < 8; k++) acc[k] += __shfl_xor(acc[k], off, 64);

  // bias + ReLU on own half (feats c*8 + k), dinv recomputed
  float di = rsqrtf((float)(cnt + 1));
  float own[8], oth[8];
#pragma unroll
  for (int k = 0; k < 8; k++)
    own[k] = fmaxf(di * acc[k] + b1[c * 8 + k], 0.f);
  // exchange halves with the c-partner lane (xor 1)
#pragma unroll
  for (int k = 0; k < 8; k++) oth[k] = __shfl_xor(own[k], 1, 64);

  // full h2 row in order: j<8 from (c==0?own:oth), j>=8 from (c==0?oth:own)
  float o = 0.f;
#pragma unroll
  for (int k = 0; k < 8; k++) {
    float lo8 = (c == 0) ? own[k] : oth[k];
    float hi8 = (c == 0) ? oth[k] : own[k];
    o += lo8 * wcol[k] + hi8 * wcol[8 + k];
  }
  if (lane < 8) gfp[(size_t)i * 8 + jp] = jv ? f2bf(di * o) : (unsigned short)0;
}

// ============ agg2 + bias + log_softmax -> out [N,7] ============
// wave per node: c = lane&1 (uint2 = 4 feats of 16B row), q = lane>>1 (32 slots)
__global__ __launch_bounds__(256) void k_agg2(const unsigned short* __restrict__ gfp,
                                              const int* __restrict__ colsrc,
                                              const int* __restrict__ rowptr,
                                              const float* __restrict__ b2,
                                              float* __restrict__ out) {
  int tid = threadIdx.x;
  int wv = tid >> 6, lane = tid & 63;
  int c = lane & 1, q = lane >> 1;
  int i = blockIdx.x * 4 + wv;                   // exact grid

  int start = rowptr[i];
  int cnt = rowptr[i + 1] - start;
  float acc[4] = {0.f, 0.f, 0.f, 0.f};
  const uint2* gp = (const uint2*)gfp;           // row i -> units i*2 + c
  for (int e = q; e < cnt; e += 32) {
    int src = colsrc[start + e];
    uint2 gv = gp[src * 2 + c];
    acc[0] += bflo(gv.x); acc[1] += bfhi(gv.x);
    acc[2] += bflo(gv.y); acc[3] += bfhi(gv.y);
  }
  if (q == 0) {                                  // self-loop
    uint2 gv = gp[i * 2 + c];
    acc[0] += bflo(gv.x); acc[1] += bfhi(gv.x);
    acc[2] += bflo(gv.y); acc[3] += bfhi(gv.y);
  }
#pragma unroll
  for (int off = 2; off < 64; off <<= 1)
#pragma unroll
    for (int k = 0; k < 4; k++) acc[k] += __shfl_xor(acc[k], off, 64);

  float di = rsqrtf((float)(cnt + 1));
  float v[4];
#pragma unroll
  for (int k = 0; k < 4; k++) {
    int f = c * 4 + k;
    v[k] = (f < 7) ? (di * acc[k] + b2[f]) : -1e30f;
  }
  float m = fmaxf(fmaxf(v[0], v[1]), fmaxf(v[2], v[3]));
  m = fmaxf(m, __shfl_xor(m, 1, 64));
  float s = __expf(v[0] - m) + __expf(v[1] - m) + __expf(v[2] - m) + __expf(v[3] - m);
  s += __shfl_xor(s, 1, 64);
  float ls = logf(s);
  if (q == 0) {
#pragma unroll
    for (int k = 0; k < 4; k++) {
      int f = c * 4 + k;
      if (f < 7) out[(size_t)i * 7 + f] = v[k] - m - ls;
    }
  }
}

extern "C" void kernel_launch(void* const* d_in, const int* in_sizes, int n_in,
                              void* d_out, int out_size, void* d_ws, size_t ws_size,
                              hipStream_t stream) {
  const float* x  = (const float*)d_in[0];
  const int*   ei = (const int*)d_in[1];     // [0..E)=src, [E..2E)=dst (int32)
  const float* W1 = (const float*)d_in[2];
  const float* b1 = (const float*)d_in[3];
  const float* W2 = (const float*)d_in[4];
  const float* b2 = (const float*)d_in[5];
  float* out = (float*)d_out;

  // workspace layout (~38 MB; d_ws ~800 MB)
  char* base = (char*)d_ws;
  int*   bcnt   = (int*)(base + 0);            //      2,048 (392*4 used)
  int*   pbase  = (int*)(base + 2048);         //      2,048 (392*4 used)
  int*   gcur   = (int*)(base + 4096);         //      2,048
  int*   rowptr = (int*)(base + 6144);         //    400,128 (N+1 used)
  int*   hist   = (int*)(base + 406272);       //    800,768 (GPART*NB*4)
  int*   colsrc = (int*)(base + 1207040);      // 12.8 MB  (ends 14,007,040)
  u32*   pairs  = (u32*)(base + 14007040);     // 12.8 MB  (ends 26,807,040)
  float* h1     = (float*)(base + 26807040);   //  6.4 MB  (ends 33,207,040)
  unsigned short* h1p = (unsigned short*)(base + 33207040); // 3.2 MB (ends 36,407,040)
  unsigned short* gfp = (unsigned short*)(base + 36407040); // 1.6 MB (ends 38,007,040)

  hipMemsetAsync(bcnt, 0, 2048, stream);

  k_hist   <<<GPART, 256, 0, stream>>>(ei + N_EDGES, hist, bcnt);
  k_gemm1  <<<(N_NODES + 63) / 64, 256, 0, stream>>>(x, W1, h1);
  k_scan391<<<1, 512, 0, stream>>>(bcnt, pbase, gcur, rowptr);
  k_part   <<<GPART, 256, 0, stream>>>(ei, ei + N_EDGES, hist, gcur, pairs);
  k_bcsr   <<<NB, 512, 0, stream>>>(pairs, pbase, colsrc, rowptr, h1, h1p);
  k_agg1g2 <<<N_NODES / 4, 256, 0, stream>>>(h1p, colsrc, rowptr, b1, W2, gfp);
  k_agg2   <<<N_NODES / 4, 256, 0, stream>>>(gfp, colsrc, rowptr, b2, out);
}

// Round 10
// 218.846 us; speedup vs baseline: 1.0700x; 1.0700x over previous
//
#include <hip/hip_runtime.h>
#include <hip/hip_bf16.h>

#define N_NODES 100000
#define N_EDGES 3200000
#define F_IN    512
#define F_H     16
#define F_OUT   7
#define NB      391                 // buckets of 256 dst nodes
#define GPART   512                 // partition blocks
#define PER_BLK 6256                // multiple of 4; 512*6256 >= 3.2M (last block short)
#define CAPB    10240               // LDS stage cap per bucket (mean 8184, sigma~90)
#define NTILES  6250                // 100000 / 16 row-tiles

typedef unsigned int u32;
typedef __attribute__((ext_vector_type(8))) __bf16 bf16x8;
typedef __attribute__((ext_vector_type(4))) float f32x4;

union FragU { uint4 q; bf16x8 v; };

static __device__ __forceinline__ float bflo(u32 u) { return __uint_as_float(u << 16); }
static __device__ __forceinline__ float bfhi(u32 u) { return __uint_as_float(u & 0xFFFF0000u); }
static __device__ __forceinline__ unsigned short f2bf(float f) {
  u32 x = __float_as_uint(f);
  x += 0x7FFF + ((x >> 16) & 1);    // round-to-nearest-even (finite values)
  return (unsigned short)(x >> 16);
}
// pack two fp32 -> two bf16 in one u32 (low16 = a, high16 = b)
static __device__ __forceinline__ u32 cvt2(float a, float b) {
  u32 r;
  asm("v_cvt_pk_bf16_f32 %0, %1, %2" : "=v"(r) : "v"(a), "v"(b));
  return r;
}

// ---------------- bucket histogram (per-block rows + bucket totals) ----------------
__global__ __launch_bounds__(256) void k_hist(const int* __restrict__ dst,
                                              int* __restrict__ hist,
                                              int* __restrict__ bcnt) {
  __shared__ int h[NB];
  int tid = threadIdx.x, blk = blockIdx.x;
  for (int b = tid; b < NB; b += 256) h[b] = 0;
  __syncthreads();
  int e0 = blk * PER_BLK;
  int n = min(PER_BLK, N_EDGES - e0);            // multiple of 4
  const int4* d4 = (const int4*)(dst + e0);
  for (int i = tid; i < (n >> 2); i += 256) {
    int4 d = d4[i];
    atomicAdd(&h[d.x >> 8], 1);
    atomicAdd(&h[d.y >> 8], 1);
    atomicAdd(&h[d.z >> 8], 1);
    atomicAdd(&h[d.w >> 8], 1);
  }
  __syncthreads();
  for (int b = tid; b < NB; b += 256) {
    int c = h[b];
    hist[blk * NB + b] = c;                      // block-major per-block counts
    if (c) atomicAdd(&bcnt[b], c);               // bucket totals
  }
}

// ---- grid=2: block 0 = bucket-base scan; block 1 = W1 bf16 B-fragment table ----
__global__ __launch_bounds__(512) void k_scanprep(const int* __restrict__ bcnt,
                                                  int* __restrict__ pbase,
                                                  int* __restrict__ gcur,
                                                  int* __restrict__ rowptr,
                                                  const float* __restrict__ W1,
                                                  uint4* __restrict__ bfragG) {
  int tid = threadIdx.x;
  if (blockIdx.x == 1) {
    // B-fragment for mfma_f32_16x16x32_bf16: lane l holds B[k=(l>>4)*8+j][col=l&15]
    for (int idx = tid; idx < NTILES * 0 + 1024; idx += 512) {  // 16 kk * 64 lanes
      int kk = idx >> 6, lane = idx & 63;
      int col = lane & 15, g = lane >> 4;
      int k0 = kk * 32 + g * 8;
      uint4 q;
      q.x = cvt2(W1[(k0 + 0) * 16 + col], W1[(k0 + 1) * 16 + col]);
      q.y = cvt2(W1[(k0 + 2) * 16 + col], W1[(k0 + 3) * 16 + col]);
      q.z = cvt2(W1[(k0 + 4) * 16 + col], W1[(k0 + 5) * 16 + col]);
      q.w = cvt2(W1[(k0 + 6) * 16 + col], W1[(k0 + 7) * 16 + col]);
      bfragG[idx] = q;
    }
    return;
  }
  __shared__ int lds[512];
  int c = (tid < NB) ? bcnt[tid] : 0;
  lds[tid] = c;
  __syncthreads();
  for (int off = 1; off < 512; off <<= 1) {
    int v = (tid >= off) ? lds[tid - off] : 0;
    __syncthreads();
    lds[tid] += v;
    __syncthreads();
  }
  int ex = lds[tid] - c;
  if (tid <= NB) pbase[tid] = ex;     // pbase[NB] == N_EDGES (total)
  if (tid < NB) gcur[tid] = ex;
  if (tid == 0) rowptr[N_NODES] = N_EDGES;
}

// ---------------- GEMM1 via MFMA: h1 = x @ W1  [N,512]x[512,16] ----------------
// One wave per 16-row tile. A: lane reads 8 consecutive fp32 of row (l&15),
// packs via v_cvt_pk_bf16_f32. B: precomputed lane-indexed table (L1-hot).
// No LDS, no barrier. 16 MFMAs per tile.
__global__ __launch_bounds__(256, 4) void k_gemm1(const float* __restrict__ x,
                                                  const uint4* __restrict__ bfragG,
                                                  float* __restrict__ h1) {
  int wid = blockIdx.x * 4 + (threadIdx.x >> 6);
  if (wid >= NTILES) return;
  int lane = threadIdx.x & 63;
  int col = lane & 15, g = lane >> 4;

  const float* xrow = x + (size_t)(wid * 16 + col) * F_IN;
  f32x4 acc = {0.f, 0.f, 0.f, 0.f};

#pragma unroll 4
  for (int kk = 0; kk < 16; kk++) {
    int k0 = kk * 32 + g * 8;
    float4 f0 = *(const float4*)(xrow + k0);
    float4 f1 = *(const float4*)(xrow + k0 + 4);
    FragU a, b;
    a.q.x = cvt2(f0.x, f0.y);
    a.q.y = cvt2(f0.z, f0.w);
    a.q.z = cvt2(f1.x, f1.y);
    a.q.w = cvt2(f1.z, f1.w);
    b.q = bfragG[kk * 64 + lane];
    acc = __builtin_amdgcn_mfma_f32_16x16x32_bf16(a.v, b.v, acc, 0, 0, 0);
  }
  // D: col = lane&15, row = (lane>>4)*4 + r
#pragma unroll
  for (int r = 0; r < 4; r++) {
    int row = g * 4 + r;
    h1[((size_t)wid * 16 + row) * F_H + col] = acc[r];
  }
}

// -------- partition scatter: reserve ranges atomically, LDS cursors --------
// pack: (dst_local << 17) | src
__global__ __launch_bounds__(256) void k_part(const int* __restrict__ src,
                                              const int* __restrict__ dst,
                                              const int* __restrict__ hist,
                                              int* __restrict__ gcur,
                                              u32* __restrict__ pairs) {
  __shared__ int lbase[NB];
  __shared__ int lcur[NB];
  int tid = threadIdx.x, blk = blockIdx.x;
  for (int b = tid; b < NB; b += 256) {
    int c = hist[blk * NB + b];
    lbase[b] = c ? atomicAdd(&gcur[b], c) : 0;
    lcur[b] = 0;
  }
  __syncthreads();
  int e0 = blk * PER_BLK;
  int n = min(PER_BLK, N_EDGES - e0);            // multiple of 4
  const int4* s4 = (const int4*)(src + e0);
  const int4* d4 = (const int4*)(dst + e0);
  for (int i = tid; i < (n >> 2); i += 256) {
    int4 sv = s4[i];
    int4 dv = d4[i];
    { int b = dv.x >> 8; u32 v = ((u32)(dv.x & 255) << 17) | (u32)sv.x;
      pairs[lbase[b] + atomicAdd(&lcur[b], 1)] = v; }
    { int b = dv.y >> 8; u32 v = ((u32)(dv.y & 255) << 17) | (u32)sv.y;
      pairs[lbase[b] + atomicAdd(&lcur[b], 1)] = v; }
    { int b = dv.z >> 8; u32 v = ((u32)(dv.z & 255) << 17) | (u32)sv.z;
      pairs[lbase[b] + atomicAdd(&lcur[b], 1)] = v; }
    { int b = dv.w >> 8; u32 v = ((u32)(dv.w & 255) << 17) | (u32)sv.w;
      pairs[lbase[b] + atomicAdd(&lcur[b], 1)] = v; }
  }
}

// ---- per-bucket CSR (pairs staged in LDS, read once) + rowptr + h1p fold ----
__global__ __launch_bounds__(512) void k_bcsr(const u32* __restrict__ pairs,
                                              const int* __restrict__ pbase,
                                              int* __restrict__ colsrc,
                                              int* __restrict__ rowptr,
                                              const float* __restrict__ h1,
                                              unsigned short* __restrict__ h1p) {
  __shared__ u32 stage[CAPB];                    // 40 KB
  __shared__ int hist256[256];
  __shared__ int scan_[256];
  __shared__ int excl[256];
  __shared__ int cur[256];
  __shared__ float sdinv[256];
  int tid = threadIdx.x, b = blockIdx.x;
  if (tid < 256) { hist256[tid] = 0; cur[tid] = 0; }
  __syncthreads();
  int base = pbase[b];
  int cnt  = pbase[b + 1] - base;
  for (int k = tid; k < cnt; k += 512) {
    u32 v = pairs[base + k];
    if (k < CAPB) stage[k] = v;
    atomicAdd(&hist256[v >> 17], 1);
  }
  __syncthreads();
  if (tid < 256) scan_[tid] = hist256[tid];
  __syncthreads();
  for (int off = 1; off < 256; off <<= 1) {
    int v = 0;
    if (tid < 256 && tid >= off) v = scan_[tid - off];
    __syncthreads();
    if (tid < 256) scan_[tid] += v;
    __syncthreads();
  }
  if (tid < 256) {
    int c = hist256[tid];
    int ex = scan_[tid] - c;
    excl[tid] = ex;
    sdinv[tid] = rsqrtf((float)(c + 1));
    int node = b * 256 + tid;
    if (node < N_NODES) rowptr[node] = base + ex;
  }
  __syncthreads();
  for (int k = tid; k < cnt; k += 512) {
    u32 v = (k < CAPB) ? stage[k] : pairs[base + k];
    int dl = v >> 17;
    colsrc[base + excl[dl] + atomicAdd(&cur[dl], 1)] = (int)(v & 0x1FFFF);
  }
  // epilogue: h1p = bf16(dinv * h1) for this bucket's nodes
  int nmax = min(256, N_NODES - b * 256);
  for (int idx = tid; idx < nmax * 16; idx += 512) {
    int ln = idx >> 4, j = idx & 15;
    size_t n = (size_t)(b * 256 + ln);
    h1p[n * 16 + j] = f2bf(h1[n * 16 + j] * sdinv[ln]);
  }
}

// ======= fused agg1 (+bias+ReLU) + GEMM2 -> gfp bf16[N][8]; dinv folded =======
// wave per node: c = lane&1 (uint4 = 8 feats of 32B row), q = lane>>1 (32 slots)
__global__ __launch_bounds__(256) void k_agg1g2(const unsigned short* __restrict__ h1p,
                                                const int* __restrict__ colsrc,
                                                const int* __restrict__ rowptr,
                                                const float* __restrict__ b1,
                                                const float* __restrict__ W2,
                                                unsigned short* __restrict__ gfp) {
  int tid = threadIdx.x;
  int wv = tid >> 6, lane = tid & 63;
  int c = lane & 1, q = lane >> 1;
  int i = blockIdx.x * 4 + wv;                   // exact grid: 25000 blocks

  int jp = lane & 7;
  bool jv = jp < 7;
  float wcol[16];
#pragma unroll
  for (int k = 0; k < 16; k++) wcol[k] = jv ? W2[k * 7 + jp] : 0.f;

  int start = rowptr[i];
  int cnt = rowptr[i + 1] - start;
  float acc[8];
#pragma unroll
  for (int k = 0; k < 8; k++) acc[k] = 0.f;

  const uint4* hp = (const uint4*)h1p;           // row i -> units i*2 + c
  for (int e = q; e < cnt; e += 32) {
    int src = colsrc[start + e];
    uint4 hv = hp[src * 2 + c];
    acc[0] += bflo(hv.x); acc[1] += bfhi(hv.x);
    acc[2] += bflo(hv.y); acc[3] += bfhi(hv.y);
    acc[4] += bflo(hv.z); acc[5] += bfhi(hv.z);
    acc[6] += bflo(hv.w); acc[7] += bfhi(hv.w);
  }
  if (q == 0) {                                  // self-loop (dinv pre-folded)
    uint4 hv = hp[i * 2 + c];
    acc[0] += bflo(hv.x); acc[1] += bfhi(hv.x);
    acc[2] += bflo(hv.y); acc[3] += bfhi(hv.y);
    acc[4] += bflo(hv.z); acc[5] += bfhi(hv.z);
    acc[6] += bflo(hv.w); acc[7] += bfhi(hv.w);
  }
#pragma unroll
  for (int off = 2; off < 64; off <<= 1)
#pragma unroll
    for (int k = 0; k < 8; k++) acc[k] += __shfl_xor(acc[k], off, 64);

  // bias + ReLU on own half (feats c*8 + k), dinv recomputed
  float di = rsqrtf((float)(cnt + 1));
  float own[8], oth[8];
#pragma unroll
  for (int k = 0; k < 8; k++)
    own[k] = fmaxf(di * acc[k] + b1[c * 8 + k], 0.f);
  // exchange halves with the c-partner lane (xor 1)
#pragma unroll
  for (int k = 0; k < 8; k++) oth[k] = __shfl_xor(own[k], 1, 64);

  // full h2 row in order: j<8 from (c==0?own:oth), j>=8 from (c==0?oth:own)
  float o = 0.f;
#pragma unroll
  for (int k = 0; k < 8; k++) {
    float lo8 = (c == 0) ? own[k] : oth[k];
    float hi8 = (c == 0) ? oth[k] : own[k];
    o += lo8 * wcol[k] + hi8 * wcol[8 + k];
  }
  if (lane < 8) gfp[(size_t)i * 8 + jp] = jv ? f2bf(di * o) : (unsigned short)0;
}

// ============ agg2 + bias + log_softmax -> out [N,7] ============
// wave per node: c = lane&1 (uint2 = 4 feats of 16B row), q = lane>>1 (32 slots)
__global__ __launch_bounds__(256) void k_agg2(const unsigned short* __restrict__ gfp,
                                              const int* __restrict__ colsrc,
                                              const int* __restrict__ rowptr,
                                              const float* __restrict__ b2,
                                              float* __restrict__ out) {
  int tid = threadIdx.x;
  int wv = tid >> 6, lane = tid & 63;
  int c = lane & 1, q = lane >> 1;
  int i = blockIdx.x * 4 + wv;                   // exact grid

  int start = rowptr[i];
  int cnt = rowptr[i + 1] - start;
  float acc[4] = {0.f, 0.f, 0.f, 0.f};
  const uint2* gp = (const uint2*)gfp;           // row i -> units i*2 + c
  for (int e = q; e < cnt; e += 32) {
    int src = colsrc[start + e];
    uint2 gv = gp[src * 2 + c];
    acc[0] += bflo(gv.x); acc[1] += bfhi(gv.x);
    acc[2] += bflo(gv.y); acc[3] += bfhi(gv.y);
  }
  if (q == 0) {                                  // self-loop
    uint2 gv = gp[i * 2 + c];
    acc[0] += bflo(gv.x); acc[1] += bfhi(gv.x);
    acc[2] += bflo(gv.y); acc[3] += bfhi(gv.y);
  }
#pragma unroll
  for (int off = 2; off < 64; off <<= 1)
#pragma unroll
    for (int k = 0; k < 4; k++) acc[k] += __shfl_xor(acc[k], off, 64);

  float di = rsqrtf((float)(cnt + 1));
  float v[4];
#pragma unroll
  for (int k = 0; k < 4; k++) {
    int f = c * 4 + k;
    v[k] = (f < 7) ? (di * acc[k] + b2[f]) : -1e30f;
  }
  float m = fmaxf(fmaxf(v[0], v[1]), fmaxf(v[2], v[3]));
  m = fmaxf(m, __shfl_xor(m, 1, 64));
  float s = __expf(v[0] - m) + __expf(v[1] - m) + __expf(v[2] - m) + __expf(v[3] - m);
  s += __shfl_xor(s, 1, 64);
  float ls = logf(s);
  if (q == 0) {
#pragma unroll
    for (int k = 0; k < 4; k++) {
      int f = c * 4 + k;
      if (f < 7) out[(size_t)i * 7 + f] = v[k] - m - ls;
    }
  }
}

extern "C" void kernel_launch(void* const* d_in, const int* in_sizes, int n_in,
                              void* d_out, int out_size, void* d_ws, size_t ws_size,
                              hipStream_t stream) {
  const float* x  = (const float*)d_in[0];
  const int*   ei = (const int*)d_in[1];     // [0..E)=src, [E..2E)=dst (int32)
  const float* W1 = (const float*)d_in[2];
  const float* b1 = (const float*)d_in[3];
  const float* W2 = (const float*)d_in[4];
  const float* b2 = (const float*)d_in[5];
  float* out = (float*)d_out;

  // workspace layout (~38 MB; d_ws ~800 MB)
  char* base = (char*)d_ws;
  int*   bcnt   = (int*)(base + 0);            //      2,048 (392*4 used)
  int*   pbase  = (int*)(base + 2048);         //      2,048 (392*4 used)
  int*   gcur   = (int*)(base + 4096);         //      2,048
  uint4* bfragG = (uint4*)(base + 6144);       //     16,384 (1024 * 16B)
  int*   rowptr = (int*)(base + 22528);        //    400,128 (N+1 used)
  int*   hist   = (int*)(base + 422656);       //    800,768 (GPART*NB*4)
  int*   colsrc = (int*)(base + 1223424);      // 12.8 MB  (ends 14,023,424)
  u32*   pairs  = (u32*)(base + 14023424);     // 12.8 MB  (ends 26,823,424)
  float* h1     = (float*)(base + 26823424);   //  6.4 MB  (ends 33,223,424)
  unsigned short* h1p = (unsigned short*)(base + 33223424); // 3.2 MB (ends 36,423,424)
  unsigned short* gfp = (unsigned short*)(base + 36423424); // 1.6 MB (ends 38,023,424)

  hipMemsetAsync(bcnt, 0, 2048, stream);

  k_hist    <<<GPART, 256, 0, stream>>>(ei + N_EDGES, hist, bcnt);
  k_scanprep<<<2, 512, 0, stream>>>(bcnt, pbase, gcur, rowptr, W1, bfragG);
  k_gemm1   <<<(NTILES + 3) / 4, 256, 0, stream>>>(x, bfragG, h1);
  k_part    <<<GPART, 256, 0, stream>>>(ei, ei + N_EDGES, hist, gcur, pairs);
  k_bcsr    <<<NB, 512, 0, stream>>>(pairs, pbase, colsrc, rowptr, h1, h1p);
  k_agg1g2  <<<N_NODES / 4, 256, 0, stream>>>(h1p, colsrc, rowptr, b1, W2, gfp);
  k_agg2    <<<N_NODES / 4, 256, 0, stream>>>(gfp, colsrc, rowptr, b2, out);
}

// Round 11
// 218.479 us; speedup vs baseline: 1.0718x; 1.0017x over previous
//
#include <hip/hip_runtime.h>
#include <hip/hip_bf16.h>

#define N_NODES 100000
#define N_EDGES 3200000
#define F_IN    512
#define F_H     16
#define F_OUT   7
#define NB      391                 // buckets of 256 dst nodes
#define GPART   512                 // partition blocks
#define PER_BLK 6256                // multiple of 4; 512*6256 >= 3.2M (last block short)
#define CAPB    10240               // LDS stage cap per bucket (mean 8184, sigma~90)
#define NTILES  6250                // 100000 / 16 row-tiles

typedef unsigned int u32;
typedef __attribute__((ext_vector_type(8))) __bf16 bf16x8;
typedef __attribute__((ext_vector_type(4))) float f32x4;

union FragU { uint4 q; bf16x8 v; };

static __device__ __forceinline__ float bflo(u32 u) { return __uint_as_float(u << 16); }
static __device__ __forceinline__ float bfhi(u32 u) { return __uint_as_float(u & 0xFFFF0000u); }
static __device__ __forceinline__ unsigned short f2bf(float f) {
  u32 x = __float_as_uint(f);
  x += 0x7FFF + ((x >> 16) & 1);    // round-to-nearest-even (finite values)
  return (unsigned short)(x >> 16);
}
// pack two fp32 -> two bf16 in one u32 (low16 = a, high16 = b)
static __device__ __forceinline__ u32 cvt2(float a, float b) {
  u32 r;
  asm("v_cvt_pk_bf16_f32 %0, %1, %2" : "=v"(r) : "v"(a), "v"(b));
  return r;
}

// ---------------- bucket histogram (per-block rows + bucket totals) ----------------
__global__ __launch_bounds__(256) void k_hist(const int* __restrict__ dst,
                                              int* __restrict__ hist,
                                              int* __restrict__ bcnt) {
  __shared__ int h[NB];
  int tid = threadIdx.x, blk = blockIdx.x;
  for (int b = tid; b < NB; b += 256) h[b] = 0;
  __syncthreads();
  int e0 = blk * PER_BLK;
  int n = min(PER_BLK, N_EDGES - e0);            // multiple of 4
  const int4* d4 = (const int4*)(dst + e0);
  for (int i = tid; i < (n >> 2); i += 256) {
    int4 d = d4[i];
    atomicAdd(&h[d.x >> 8], 1);
    atomicAdd(&h[d.y >> 8], 1);
    atomicAdd(&h[d.z >> 8], 1);
    atomicAdd(&h[d.w >> 8], 1);
  }
  __syncthreads();
  for (int b = tid; b < NB; b += 256) {
    int c = h[b];
    hist[blk * NB + b] = c;                      // block-major per-block counts
    if (c) atomicAdd(&bcnt[b], c);               // bucket totals
  }
}

// ---- grid=2: block 0 = bucket-base scan; block 1 = W1 bf16 B-fragment table ----
__global__ __launch_bounds__(512) void k_scanprep(const int* __restrict__ bcnt,
                                                  int* __restrict__ pbase,
                                                  int* __restrict__ gcur,
                                                  int* __restrict__ rowptr,
                                                  const float* __restrict__ W1,
                                                  uint4* __restrict__ bfragG) {
  int tid = threadIdx.x;
  if (blockIdx.x == 1) {
    // B-fragment for mfma_f32_16x16x32_bf16: lane l holds B[k=(l>>4)*8+j][col=l&15]
    for (int idx = tid; idx < 1024; idx += 512) {  // 16 kk * 64 lanes
      int kk = idx >> 6, lane = idx & 63;
      int col = lane & 15, g = lane >> 4;
      int k0 = kk * 32 + g * 8;
      uint4 q;
      q.x = cvt2(W1[(k0 + 0) * 16 + col], W1[(k0 + 1) * 16 + col]);
      q.y = cvt2(W1[(k0 + 2) * 16 + col], W1[(k0 + 3) * 16 + col]);
      q.z = cvt2(W1[(k0 + 4) * 16 + col], W1[(k0 + 5) * 16 + col]);
      q.w = cvt2(W1[(k0 + 6) * 16 + col], W1[(k0 + 7) * 16 + col]);
      bfragG[idx] = q;
    }
    return;
  }
  __shared__ int lds[512];
  int c = (tid < NB) ? bcnt[tid] : 0;
  lds[tid] = c;
  __syncthreads();
  for (int off = 1; off < 512; off <<= 1) {
    int v = (tid >= off) ? lds[tid - off] : 0;
    __syncthreads();
    lds[tid] += v;
    __syncthreads();
  }
  int ex = lds[tid] - c;
  if (tid <= NB) pbase[tid] = ex;     // pbase[NB] == N_EDGES (total)
  if (tid < NB) gcur[tid] = ex;
  if (tid == 0) rowptr[N_NODES] = N_EDGES;
}

// ---------------- GEMM1 via MFMA + LDS-staged coalesced loads ----------------
// Block = 4 waves = 64 rows. Per kk: stage [64 rows][32 k] bf16 into LDS
// (80 B row stride -> 2-way bank conflicts = free), double-buffered, one
// barrier per kk. Staging loads are dense 128 B per row (8 lanes x float4).
// Fragment read = 1 ds_read_b128 per wave per kk. 16 MFMAs per wave.
__global__ __launch_bounds__(256) void k_gemm1(const float* __restrict__ x,
                                               const uint4* __restrict__ bfragG,
                                               float* __restrict__ h1) {
  __shared__ __align__(16) char ldsbuf[2][64 * 80];   // 10 KB
  int tid = threadIdx.x;
  int blockRow0 = blockIdx.x * 64;

  // staging mapping: thread covers rows r0 (=tid>>3) and r1 (=r0+32), slot s=tid&7
  int r0 = tid >> 3, r1 = r0 + 32, s = tid & 7;
  bool ok1 = (blockRow0 + r1) < N_NODES;             // r0 rows always < N
  const float* x0 = x + (size_t)(blockRow0 + r0) * F_IN + s * 4;
  const float* x1 = x + (size_t)(blockRow0 + r1) * F_IN + s * 4;

  // fragment mapping
  int wv = tid >> 6, lane = tid & 63;
  int col = lane & 15, g = lane >> 4;
  int wid = blockIdx.x * 4 + wv;
  int fragRow = wv * 16 + col;

  f32x4 acc = {0.f, 0.f, 0.f, 0.f};

  // prologue: stage kk=0 into buf 0
  {
    float4 fA = *(const float4*)(x0);
    float4 fB = ok1 ? *(const float4*)(x1) : make_float4(0.f, 0.f, 0.f, 0.f);
    uint2 qA = {cvt2(fA.x, fA.y), cvt2(fA.z, fA.w)};
    uint2 qB = {cvt2(fB.x, fB.y), cvt2(fB.z, fB.w)};
    *(uint2*)(&ldsbuf[0][r0 * 80 + s * 8]) = qA;
    *(uint2*)(&ldsbuf[0][r1 * 80 + s * 8]) = qB;
  }
  __syncthreads();

#pragma unroll
  for (int kk = 0; kk < 16; kk++) {
    int cur = kk & 1;
    // issue next-tile global loads early (latency hides under MFMA)
    float4 fA, fB;
    if (kk < 15) {
      fA = *(const float4*)(x0 + (kk + 1) * 32);
      fB = ok1 ? *(const float4*)(x1 + (kk + 1) * 32) : make_float4(0.f, 0.f, 0.f, 0.f);
    }
    FragU a, b;
    a.q = *(const uint4*)(&ldsbuf[cur][fragRow * 80 + g * 16]);
    b.q = bfragG[kk * 64 + lane];
    acc = __builtin_amdgcn_mfma_f32_16x16x32_bf16(a.v, b.v, acc, 0, 0, 0);
    if (kk < 15) {
      uint2 qA = {cvt2(fA.x, fA.y), cvt2(fA.z, fA.w)};
      uint2 qB = {cvt2(fB.x, fB.y), cvt2(fB.z, fB.w)};
      *(uint2*)(&ldsbuf[cur ^ 1][r0 * 80 + s * 8]) = qA;
      *(uint2*)(&ldsbuf[cur ^ 1][r1 * 80 + s * 8]) = qB;
    }
    __syncthreads();
  }

  // D: col = lane&15 (feature), row = (lane>>4)*4 + r (node within tile)
#pragma unroll
  for (int r = 0; r < 4; r++) {
    int node = wid * 16 + g * 4 + r;
    if (node < N_NODES) h1[(size_t)node * F_H + col] = acc[r];
  }
}

// -------- partition scatter: reserve ranges atomically, LDS cursors --------
// pack: (dst_local << 17) | src
__global__ __launch_bounds__(256) void k_part(const int* __restrict__ src,
                                              const int* __restrict__ dst,
                                              const int* __restrict__ hist,
                                              int* __restrict__ gcur,
                                              u32* __restrict__ pairs) {
  __shared__ int lbase[NB];
  __shared__ int lcur[NB];
  int tid = threadIdx.x, blk = blockIdx.x;
  for (int b = tid; b < NB; b += 256) {
    int c = hist[blk * NB + b];
    lbase[b] = c ? atomicAdd(&gcur[b], c) : 0;
    lcur[b] = 0;
  }
  __syncthreads();
  int e0 = blk * PER_BLK;
  int n = min(PER_BLK, N_EDGES - e0);            // multiple of 4
  const int4* s4 = (const int4*)(src + e0);
  const int4* d4 = (const int4*)(dst + e0);
  for (int i = tid; i < (n >> 2); i += 256) {
    int4 sv = s4[i];
    int4 dv = d4[i];
    { int b = dv.x >> 8; u32 v = ((u32)(dv.x & 255) << 17) | (u32)sv.x;
      pairs[lbase[b] + atomicAdd(&lcur[b], 1)] = v; }
    { int b = dv.y >> 8; u32 v = ((u32)(dv.y & 255) << 17) | (u32)sv.y;
      pairs[lbase[b] + atomicAdd(&lcur[b], 1)] = v; }
    { int b = dv.z >> 8; u32 v = ((u32)(dv.z & 255) << 17) | (u32)sv.z;
      pairs[lbase[b] + atomicAdd(&lcur[b], 1)] = v; }
    { int b = dv.w >> 8; u32 v = ((u32)(dv.w & 255) << 17) | (u32)sv.w;
      pairs[lbase[b] + atomicAdd(&lcur[b], 1)] = v; }
  }
}

// ---- per-bucket CSR (pairs staged in LDS, read once) + rowptr + h1p fold ----
__global__ __launch_bounds__(512) void k_bcsr(const u32* __restrict__ pairs,
                                              const int* __restrict__ pbase,
                                              int* __restrict__ colsrc,
                                              int* __restrict__ rowptr,
                                              const float* __restrict__ h1,
                                              unsigned short* __restrict__ h1p) {
  __shared__ u32 stage[CAPB];                    // 40 KB
  __shared__ int hist256[256];
  __shared__ int scan_[256];
  __shared__ int excl[256];
  __shared__ int cur[256];
  __shared__ float sdinv[256];
  int tid = threadIdx.x, b = blockIdx.x;
  if (tid < 256) { hist256[tid] = 0; cur[tid] = 0; }
  __syncthreads();
  int base = pbase[b];
  int cnt  = pbase[b + 1] - base;
  for (int k = tid; k < cnt; k += 512) {
    u32 v = pairs[base + k];
    if (k < CAPB) stage[k] = v;
    atomicAdd(&hist256[v >> 17], 1);
  }
  __syncthreads();
  if (tid < 256) scan_[tid] = hist256[tid];
  __syncthreads();
  for (int off = 1; off < 256; off <<= 1) {
    int v = 0;
    if (tid < 256 && tid >= off) v = scan_[tid - off];
    __syncthreads();
    if (tid < 256) scan_[tid] += v;
    __syncthreads();
  }
  if (tid < 256) {
    int c = hist256[tid];
    int ex = scan_[tid] - c;
    excl[tid] = ex;
    sdinv[tid] = rsqrtf((float)(c + 1));
    int node = b * 256 + tid;
    if (node < N_NODES) rowptr[node] = base + ex;
  }
  __syncthreads();
  for (int k = tid; k < cnt; k += 512) {
    u32 v = (k < CAPB) ? stage[k] : pairs[base + k];
    int dl = v >> 17;
    colsrc[base + excl[dl] + atomicAdd(&cur[dl], 1)] = (int)(v & 0x1FFFF);
  }
  // epilogue: h1p = bf16(dinv * h1) for this bucket's nodes
  int nmax = min(256, N_NODES - b * 256);
  for (int idx = tid; idx < nmax * 16; idx += 512) {
    int ln = idx >> 4, j = idx & 15;
    size_t n = (size_t)(b * 256 + ln);
    h1p[n * 16 + j] = f2bf(h1[n * 16 + j] * sdinv[ln]);
  }
}

// ======= fused agg1 (+bias+ReLU) + GEMM2 -> gfp bf16[N][8]; dinv folded =======
// wave per node: c = lane&1 (uint4 = 8 feats of 32B row), q = lane>>1 (32 slots)
__global__ __launch_bounds__(256) void k_agg1g2(const unsigned short* __restrict__ h1p,
                                                const int* __restrict__ colsrc,
                                                const int* __restrict__ rowptr,
                                                const float* __restrict__ b1,
                                                const float* __restrict__ W2,
                                                unsigned short* __restrict__ gfp) {
  int tid = threadIdx.x;
  int wv = tid >> 6, lane = tid & 63;
  int c = lane & 1, q = lane >> 1;
  int i = blockIdx.x * 4 + wv;                   // exact grid: 25000 blocks

  int jp = lane & 7;
  bool jv = jp < 7;
  float wcol[16];
#pragma unroll
  for (int k = 0; k < 16; k++) wcol[k] = jv ? W2[k * 7 + jp] : 0.f;

  int start = rowptr[i];
  int cnt = rowptr[i + 1] - start;
  float acc[8];
#pragma unroll
  for (int k = 0; k < 8; k++) acc[k] = 0.f;

  const uint4* hp = (const uint4*)h1p;           // row i -> units i*2 + c
  for (int e = q; e < cnt; e += 32) {
    int src = colsrc[start + e];
    uint4 hv = hp[src * 2 + c];
    acc[0] += bflo(hv.x); acc[1] += bfhi(hv.x);
    acc[2] += bflo(hv.y); acc[3] += bfhi(hv.y);
    acc[4] += bflo(hv.z); acc[5] += bfhi(hv.z);
    acc[6] += bflo(hv.w); acc[7] += bfhi(hv.w);
  }
  if (q == 0) {                                  // self-loop (dinv pre-folded)
    uint4 hv = hp[i * 2 + c];
    acc[0] += bflo(hv.x); acc[1] += bfhi(hv.x);
    acc[2] += bflo(hv.y); acc[3] += bfhi(hv.y);
    acc[4] += bflo(hv.z); acc[5] += bfhi(hv.z);
    acc[6] += bflo(hv.w); acc[7] += bfhi(hv.w);
  }
#pragma unroll
  for (int off = 2; off < 64; off <<= 1)
#pragma unroll
    for (int k = 0; k < 8; k++) acc[k] += __shfl_xor(acc[k], off, 64);

  // bias + ReLU on own half (feats c*8 + k), dinv recomputed
  float di = rsqrtf((float)(cnt + 1));
  float own[8], oth[8];
#pragma unroll
  for (int k = 0; k < 8; k++)
    own[k] = fmaxf(di * acc[k] + b1[c * 8 + k], 0.f);
  // exchange halves with the c-partner lane (xor 1)
#pragma unroll
  for (int k = 0; k < 8; k++) oth[k] = __shfl_xor(own[k], 1, 64);

  // full h2 row in order: j<8 from (c==0?own:oth), j>=8 from (c==0?oth:own)
  float o = 0.f;
#pragma unroll
  for (int k = 0; k < 8; k++) {
    float lo8 = (c == 0) ? own[k] : oth[k];
    float hi8 = (c == 0) ? oth[k] : own[k];
    o += lo8 * wcol[k] + hi8 * wcol[8 + k];
  }
  if (lane < 8) gfp[(size_t)i * 8 + jp] = jv ? f2bf(di * o) : (unsigned short)0;
}

// ============ agg2 + bias + log_softmax -> out [N,7] ============
// wave per node: c = lane&1 (uint2 = 4 feats of 16B row), q = lane>>1 (32 slots)
__global__ __launch_bounds__(256) void k_agg2(const unsigned short* __restrict__ gfp,
                                              const int* __restrict__ colsrc,
                                              const int* __restrict__ rowptr,
                                              const float* __restrict__ b2,
                                              float* __restrict__ out) {
  int tid = threadIdx.x;
  int wv = tid >> 6, lane = tid & 63;
  int c = lane & 1, q = lane >> 1;
  int i = blockIdx.x * 4 + wv;                   // exact grid

  int start = rowptr[i];
  int cnt = rowptr[i + 1] - start;
  float acc[4] = {0.f, 0.f, 0.f, 0.f};
  const uint2* gp = (const uint2*)gfp;           // row i -> units i*2 + c
  for (int e = q; e < cnt; e += 32) {
    int src = colsrc[start + e];
    uint2 gv = gp[src * 2 + c];
    acc[0] += bflo(gv.x); acc[1] += bfhi(gv.x);
    acc[2] += bflo(gv.y); acc[3] += bfhi(gv.y);
  }
  if (q == 0) {                                  // self-loop
    uint2 gv = gp[i * 2 + c];
    acc[0] += bflo(gv.x); acc[1] += bfhi(gv.x);
    acc[2] += bflo(gv.y); acc[3] += bfhi(gv.y);
  }
#pragma unroll
  for (int off = 2; off < 64; off <<= 1)
#pragma unroll
    for (int k = 0; k < 4; k++) acc[k] += __shfl_xor(acc[k], off, 64);

  float di = rsqrtf((float)(cnt + 1));
  float v[4];
#pragma unroll
  for (int k = 0; k < 4; k++) {
    int f = c * 4 + k;
    v[k] = (f < 7) ? (di * acc[k] + b2[f]) : -1e30f;
  }
  float m = fmaxf(fmaxf(v[0], v[1]), fmaxf(v[2], v[3]));
  m = fmaxf(m, __shfl_xor(m, 1, 64));
  float s = __expf(v[0] - m) + __expf(v[1] - m) + __expf(v[2] - m) + __expf(v[3] - m);
  s += __shfl_xor(s, 1, 64);
  float ls = logf(s);
  if (q == 0) {
#pragma unroll
    for (int k = 0; k < 4; k++) {
      int f = c * 4 + k;
      if (f < 7) out[(size_t)i * 7 + f] = v[k] - m - ls;
    }
  }
}

extern "C" void kernel_launch(void* const* d_in, const int* in_sizes, int n_in,
                              void* d_out, int out_size, void* d_ws, size_t ws_size,
                              hipStream_t stream) {
  const float* x  = (const float*)d_in[0];
  const int*   ei = (const int*)d_in[1];     // [0..E)=src, [E..2E)=dst (int32)
  const float* W1 = (const float*)d_in[2];
  const float* b1 = (const float*)d_in[3];
  const float* W2 = (const float*)d_in[4];
  const float* b2 = (const float*)d_in[5];
  float* out = (float*)d_out;

  // workspace layout (~38 MB; d_ws ~800 MB)
  char* base = (char*)d_ws;
  int*   bcnt   = (int*)(base + 0);            //      2,048 (392*4 used)
  int*   pbase  = (int*)(base + 2048);         //      2,048 (392*4 used)
  int*   gcur   = (int*)(base + 4096);         //      2,048
  uint4* bfragG = (uint4*)(base + 6144);       //     16,384 (1024 * 16B)
  int*   rowptr = (int*)(base + 22528);        //    400,128 (N+1 used)
  int*   hist   = (int*)(base + 422656);       //    800,768 (GPART*NB*4)
  int*   colsrc = (int*)(base + 1223424);      // 12.8 MB  (ends 14,023,424)
  u32*   pairs  = (u32*)(base + 14023424);     // 12.8 MB  (ends 26,823,424)
  float* h1     = (float*)(base + 26823424);   //  6.4 MB  (ends 33,223,424)
  unsigned short* h1p = (unsigned short*)(base + 33223424); // 3.2 MB (ends 36,423,424)
  unsigned short* gfp = (unsigned short*)(base + 36423424); // 1.6 MB (ends 38,023,424)

  hipMemsetAsync(bcnt, 0, 2048, stream);

  k_hist    <<<GPART, 256, 0, stream>>>(ei + N_EDGES, hist, bcnt);
  k_scanprep<<<2, 512, 0, stream>>>(bcnt, pbase, gcur, rowptr, W1, bfragG);
  k_gemm1   <<<(NTILES + 3) / 4, 256, 0, stream>>>(x, bfragG, h1);
  k_part    <<<GPART, 256, 0, stream>>>(ei, ei + N_EDGES, hist, gcur, pairs);
  k_bcsr    <<<NB, 512, 0, stream>>>(pairs, pbase, colsrc, rowptr, h1, h1p);
  k_agg1g2  <<<N_NODES / 4, 256, 0, stream>>>(h1p, colsrc, rowptr, b1, W2, gfp);
  k_agg2    <<<N_NODES / 4, 256, 0, stream>>>(gfp, colsrc, rowptr, b2, out);
}